// Round 6
// baseline (121.366 us; speedup 1.0000x reference)
//
#include <hip/hip_runtime.h>
#include <cstdint>

#pragma clang fp contract(off)

#define R_N   2000
#define C1    21
#define NCLS  20
#define OUT_LBL   200000
#define OUT_KEEP  240000
#define FMARGIN   4.0f      // abs err bound of f32 (inter - 0.3*uni) ~0.7 px^2; 4.0 = 5x safety

__device__ __forceinline__ double read_dim(const void* p) {
  int iv = *(const int*)p;
  if (iv >= 1 && iv <= 1000000) return (double)iv;
  float fv = *(const float*)p;
  if (fv >= 1.0f && fv <= 1000000.0f) return (double)fv;
  return *(const double*)p;
}

// ---- kernel 1: transposed f64 tables: prob_t[cls*R_N+r], tab4[(cls*R_N+r)*4]={dy,dx,exp(dh),exp(dw)}
__global__ __launch_bounds__(256) void prep_kernel(
    const float* __restrict__ score, const float* __restrict__ loc,
    double* __restrict__ tab4, double* __restrict__ prob_t)
{
  int r = blockIdx.x * 256 + threadIdx.x;
  if (r >= R_N) return;
  const float* sc = score + r * C1;
  double m = (double)sc[0];
  #pragma unroll
  for (int k = 1; k < C1; ++k) m = fmax(m, (double)sc[k]);
  double e[C1]; double s = 0.0;
  #pragma unroll
  for (int k = 0; k < C1; ++k) { e[k] = exp((double)sc[k] - m); s += e[k]; }
  for (int c = 0; c < NCLS; ++c)
    prob_t[c * R_N + r] = e[c + 1] / s;
  for (int c = 0; c < NCLS; ++c) {
    const float* l4 = loc + r * 84 + (c + 1) * 4;
    double* o = tab4 + (size_t)(c * R_N + r) * 4;
    o[0] = (double)l4[0];
    o[1] = (double)l4[1];
    o[2] = exp((double)l4[2]);
    o[3] = exp((double)l4[3]);
  }
}

// ---- kernel 2: decode + sort + precomputed-bitmatrix NMS ----
__global__ __launch_bounds__(256) void det_kernel(
    const float* __restrict__ rois, const float* __restrict__ loc,
    const float* __restrict__ score,
    const void* __restrict__ hptr, const void* __restrict__ wptr,
    float* __restrict__ out,
    const double* __restrict__ tab4, const double* __restrict__ prob_t,
    int use_ws)
{
  __shared__ double sbd[R_N][4];                 // decoded f64 boxes by orig idx (64000 B)
  __shared__ __align__(16) unsigned char upool[57344]; // keys, then sboxf/sidx/sprob
  __shared__ double klist64[2][64][5];
  __shared__ float  klist32[2][64][5];
  __shared__ int kcnt[2];
  __shared__ int wsum[4];

  ulonglong2* keys  = (ulonglong2*)upool;        // [2048] (pre-sort / sort)
  float (*sboxf)[5] = (float(*)[5])upool;        // [2048][5] post-sort (aliases keys)
  int*   sidx_      = (int*)(upool + 40960);     // [2048]
  float* sprob_     = (float*)(upool + 49152);   // [2048]

  const int cls = blockIdx.x;
  const int t = threadIdx.x;
  const int lane = t & 63, wid = t >> 6;
  const double H = read_dim(hptr), W = read_dim(wptr);

  // ---- phase 1: decode (coalesced r = t + 256u) ----
  ulonglong2 rk[8];
  int vmask = 0;
  #pragma unroll
  for (int u = 0; u < 8; ++u) {
    int r = t + 256 * u;
    rk[u] = make_ulonglong2(0ull, 0ull);
    if (r < R_N) {
      double p, dy, dx, eh, ew;
      if (use_ws) {
        p = prob_t[cls * R_N + r];
        const double* o = tab4 + (size_t)(cls * R_N + r) * 4;
        dy = o[0]; dx = o[1]; eh = o[2]; ew = o[3];
      } else {
        const float* sc = score + r * C1;
        double m = (double)sc[0];
        #pragma unroll
        for (int k = 1; k < C1; ++k) m = fmax(m, (double)sc[k]);
        double s = 0.0;
        #pragma unroll
        for (int k = 0; k < C1; ++k) s += exp((double)sc[k] - m);
        const float* l4 = loc + r * 84 + (cls + 1) * 4;
        p = exp((double)sc[cls + 1] - m) / s;
        dy = (double)l4[0]; dx = (double)l4[1];
        eh = exp((double)l4[2]); ew = exp((double)l4[3]);
      }
      double b0 = (double)rois[r*4+0], b1 = (double)rois[r*4+1];
      double b2 = (double)rois[r*4+2], b3 = (double)rois[r*4+3];
      double sh  = b2 - b0,       sw  = b3 - b1;
      double scy = b0 + 0.5*sh,   scx = b1 + 0.5*sw;
      double cy = dy*sh + scy,    cx = dx*sw + scx;
      double hh = eh*sh,          ww = ew*sw;
      double y1 = fmin(fmax(cy - 0.5*hh, 0.0), H);
      double x1 = fmin(fmax(cx - 0.5*ww, 0.0), W);
      double y2 = fmin(fmax(cy + 0.5*hh, 0.0), H);
      double x2 = fmin(fmax(cx + 0.5*ww, 0.0), W);
      sbd[r][0]=y1; sbd[r][1]=x1; sbd[r][2]=y2; sbd[r][3]=x2;
      if (p > 0.05) {
        rk[u] = make_ulonglong2((unsigned long long)__double_as_longlong(p),
                                (unsigned long long)(unsigned int)(~r));
        vmask |= 1 << u;
      }
    }
  }

  // ---- phase 2: compaction (order irrelevant pre-sort) ----
  int cnt = __popc(vmask);
  int x = cnt;
  #pragma unroll
  for (int off = 1; off < 64; off <<= 1) {
    int y = __shfl_up(x, off);
    if (lane >= off) x += y;
  }
  if (lane == 63) wsum[wid] = x;
  __syncthreads();
  int woff = 0;
  #pragma unroll
  for (int w2 = 0; w2 < 4; ++w2) { int s = wsum[w2]; if (w2 < wid) woff += s; }
  const int V = wsum[0] + wsum[1] + wsum[2] + wsum[3];
  int pos = woff + x - cnt;
  #pragma unroll
  for (int u = 0; u < 8; ++u)
    if ((vmask >> u) & 1) keys[pos++] = rk[u];

  int NSORT = 64; while (NSORT < V) NSORT <<= 1;
  for (int j = V + t; j < NSORT; j += 256)
    keys[j] = make_ulonglong2(0ull, (unsigned long long)(unsigned int)(~(unsigned)j));
  __syncthreads();

  // ---- phase 3: bitonic sort, descending (prob desc, idx asc) ----
  for (int k = 2; k <= NSORT; k <<= 1) {
    for (int js = k >> 1; js > 0; js >>= 1) {
      for (int p = t; p < (NSORT >> 1); p += 256) {
        int i = ((p & ~(js - 1)) << 1) | (p & (js - 1));
        int j = i | js;
        ulonglong2 a = keys[i], b = keys[j];
        bool altb = (a.x < b.x) || (a.x == b.x && a.y < b.y);
        if (altb == ((i & k) == 0)) { keys[i] = b; keys[j] = a; }
      }
      __syncthreads();
    }
  }

  // ---- phase 4: transition keys -> sboxf/sidx/sprob (aliased), load slot regs ----
  ulonglong2 kreg[8];
  #pragma unroll
  for (int u = 0; u < 8; ++u) {
    int j = t + 256 * u;
    kreg[u] = (j < NSORT) ? keys[j] : make_ulonglong2(0ull, 0ull);
  }
  __syncthreads();                                // all keys reads done before alias writes

  float fx0[8], fx1[8], fx2[8], fx3[8], far5[8];
  unsigned am = 0;
  #pragma unroll
  for (int u = 0; u < 8; ++u) {
    int j = t + 256 * u;
    fx0[u]=fx1[u]=fx2[u]=fx3[u]=0.f; far5[u]=0.f;
    if (j < NSORT) {
      if (j < V) {
        int idx = (int)(~(unsigned)kreg[u].y);
        double a0=sbd[idx][0], a1=sbd[idx][1], a2=sbd[idx][2], a3=sbd[idx][3];
        float f0=(float)a0, f1=(float)a1, f2=(float)a2, f3=(float)a3;
        float fa=(float)((a2-a0)*(a3-a1));
        sboxf[j][0]=f0; sboxf[j][1]=f1; sboxf[j][2]=f2; sboxf[j][3]=f3; sboxf[j][4]=fa;
        sidx_[j]=idx;
        sprob_[j]=(float)__longlong_as_double((long long)kreg[u].x);
        fx0[u]=f0; fx1[u]=f1; fx2[u]=f2; fx3[u]=f3; far5[u]=fa;
        am |= 1u << u;
      } else {
        sboxf[j][0]=sboxf[j][1]=sboxf[j][2]=sboxf[j][3]=sboxf[j][4]=0.f;
        sidx_[j]=0; sprob_[j]=0.f;
      }
    }
  }
  __syncthreads();

  // ---- phase 5: precompute within-chunk kill/amb bit rows (fully parallel) ----
  // thread t owns slot s = t+256q = 64*(wid+4q)+lane -> row 'lane' of chunk wid+4q
  unsigned long long rowkill[8], rowamb[8];
  #pragma unroll
  for (int q = 0; q < 8; ++q) {
    rowkill[q] = 0ull; rowamb[q] = 0ull;
    if (256 * q >= V) break;
    int ch = wid + 4 * q;
    if (64 * ch >= V) continue;                   // chunk doesn't exist for this wave
    int chbase = 64 * ch;
    float m0=fx0[q], m1=fx1[q], m2=fx2[q], m3=fx3[q], ma=far5[q];
    for (int jj = lane + 1; jj < 64; ++jj) {      // bits only for j > i(=lane)
      float b0=sboxf[chbase+jj][0], b1=sboxf[chbase+jj][1];
      float b2=sboxf[chbase+jj][2], b3=sboxf[chbase+jj][3], ba=sboxf[chbase+jj][4];
      float ty=fmaxf(m0,b0), tx=fmaxf(m1,b1);
      float by=fminf(m2,b2), bz=fminf(m3,b3);
      float w0=fmaxf(by-ty,0.f), w1=fmaxf(bz-tx,0.f);
      float inter=w0*w1;
      float uni=fmaxf(ma+ba-inter, 1e-9f);
      float rhs=0.3f*uni;
      if (inter > rhs + FMARGIN)      rowkill[q] |= 1ull << jj;
      else if (inter > rhs - FMARGIN) rowamb[q]  |= 1ull << jj;
    }
  }
  __syncthreads();

  // ---- phase 6: NMS: bitmask scan resolve + lazy cross-chunk suppression ----
  #pragma unroll
  for (int q = 0; q < 8; ++q) {
    if (256 * q >= V) break;
    for (int sub = 0; sub < 4; ++sub) {
      const int ch = 4 * q + sub;
      if (64 * ch >= V) break;
      const int buf = ch & 1;
      const int chbase = 64 * ch;
      if (wid == sub) {
        const int s = chbase + lane;
        unsigned long long m = __ballot(((am >> q) & 1u) != 0u);
        unsigned long long kept = 0;
        while (m) {
          int i = __ffsll(m) - 1;
          kept |= 1ull << i;
          m &= ~(1ull << i);
          unsigned long long rk_i = __shfl(rowkill[q], i);
          unsigned long long ra_i = __shfl(rowamb[q], i);
          unsigned long long ambhit = ra_i & m;
          m &= ~rk_i;
          if (ambhit) {                            // rare: exact f64 round
            bool exkill = false;
            if ((ambhit >> lane) & 1ull) {
              int ii = sidx_[chbase + i];          // wave-uniform read
              int jj = sidx_[s];
              double b0=sbd[ii][0], b1=sbd[ii][1], b2=sbd[ii][2], b3=sbd[ii][3];
              double a0=sbd[jj][0], a1=sbd[jj][1], a2=sbd[jj][2], a3=sbd[jj][3];
              double bar=(b2-b0)*(b3-b1), aar=(a2-a0)*(a3-a1);
              double ty_=fmax(b0,a0), tx_=fmax(b1,a1);
              double by_=fmin(b2,a2), bz_=fmin(b3,a3);
              double w0_=fmax(by_-ty_,0.0), w1_=fmax(bz_-tx_,0.0);
              double in_=w0_*w1_;
              double un_=bar+aar-in_;
              exkill = in_/fmax(un_,1e-9) > 0.3;
            }
            m &= ~__ballot(exkill);
          }
        }
        am &= ~(1u << q);                          // chunk resolved
        if ((kept >> lane) & 1ull) {
          int kpos = (int)__popcll(kept & ((1ull << lane) - 1ull));
          int idx = sidx_[s];
          double d0=sbd[idx][0], d1=sbd[idx][1], d2=sbd[idx][2], d3=sbd[idx][3];
          double dar=(d2-d0)*(d3-d1);
          klist64[buf][kpos][0]=d0; klist64[buf][kpos][1]=d1;
          klist64[buf][kpos][2]=d2; klist64[buf][kpos][3]=d3; klist64[buf][kpos][4]=dar;
          klist32[buf][kpos][0]=fx0[q]; klist32[buf][kpos][1]=fx1[q];
          klist32[buf][kpos][2]=fx2[q]; klist32[buf][kpos][3]=fx3[q]; klist32[buf][kpos][4]=far5[q];
          int row = cls * R_N + s;
          out[row*5+0]=(float)d0; out[row*5+1]=(float)d1;
          out[row*5+2]=(float)d2; out[row*5+3]=(float)d3;
          out[row*5+4]=sprob_[s];
          out[OUT_LBL  + row] = (float)(cls + 1);
          out[OUT_KEEP + row] = 1.0f;
        }
        if (lane == 0) kcnt[buf] = (int)__popcll(kept);
      }
      __syncthreads();
      // cross suppression of future slots (f32 fast, f64 exact fallback)
      const int nk = kcnt[buf];
      const int jmin = 64 * (ch + 1);
      for (int n = 0; n < nk; ++n) {
        float k0=klist32[buf][n][0], k1=klist32[buf][n][1];
        float k2=klist32[buf][n][2], k3=klist32[buf][n][3], ka=klist32[buf][n][4];
        #pragma unroll
        for (int q2 = 0; q2 < 8; ++q2) {
          if (256 * q2 >= V) break;
          int j2 = t + 256 * q2;
          if (((am >> q2) & 1u) && j2 >= jmin) {
            float ty=fmaxf(k0,fx0[q2]), tx=fmaxf(k1,fx1[q2]);
            float by=fminf(k2,fx2[q2]), bz=fminf(k3,fx3[q2]);
            float w0=fmaxf(by-ty,0.f), w1=fmaxf(bz-tx,0.f);
            float inter=w0*w1;
            float uni=fmaxf(ka+far5[q2]-inter, 1e-9f);
            float rhs=0.3f*uni;
            if (inter > rhs + FMARGIN) {
              am &= ~(1u << q2);
            } else if (inter > rhs - FMARGIN) {
              int idx = sidx_[j2];
              double a0=sbd[idx][0], a1=sbd[idx][1], a2=sbd[idx][2], a3=sbd[idx][3];
              double ar_=(a2-a0)*(a3-a1);
              double b0=klist64[buf][n][0], b1=klist64[buf][n][1];
              double b2=klist64[buf][n][2], b3=klist64[buf][n][3], br=klist64[buf][n][4];
              double ty_=fmax(b0,a0), tx_=fmax(b1,a1);
              double by_=fmin(b2,a2), bz_=fmin(b3,a3);
              double w0_=fmax(by_-ty_,0.0), w1_=fmax(bz_-tx_,0.0);
              double in_=w0_*w1_;
              double un_=br+ar_-in_;
              if (in_/fmax(un_,1e-9) > 0.3) am &= ~(1u << q2);
            }
          }
        }
      }
    }
  }
}

extern "C" void kernel_launch(void* const* d_in, const int* in_sizes, int n_in,
                              void* d_out, int out_size, void* d_ws, size_t ws_size,
                              hipStream_t stream) {
  const float* rois  = (const float*)d_in[0];
  const float* loc   = (const float*)d_in[1];
  const float* score = (const float*)d_in[2];
  const void*  hp    = d_in[3];
  const void*  wp    = d_in[4];
  float* out = (float*)d_out;

  const size_t need = (size_t)(NCLS * R_N * 4 + NCLS * R_N) * sizeof(double); // 1.6 MB
  double* tab4   = (double*)d_ws;
  double* prob_t = tab4 + (size_t)NCLS * R_N * 4;
  int use_ws = (ws_size >= need) ? 1 : 0;

  hipMemsetAsync(d_out, 0, (size_t)out_size * sizeof(float), stream);
  if (use_ws) {
    prep_kernel<<<dim3((R_N + 255)/256), dim3(256), 0, stream>>>(score, loc, tab4, prob_t);
  }
  det_kernel<<<dim3(NCLS), dim3(256), 0, stream>>>(rois, loc, score, hp, wp, out,
                                                   tab4, prob_t, use_ws);
}

// Round 7
// 112.843 us; speedup vs baseline: 1.0755x; 1.0755x over previous
//
#include <hip/hip_runtime.h>
#include <cstdint>

#pragma clang fp contract(off)

#define R_N   2000
#define C1    21
#define NCLS  20
#define SLOTS 2048
#define PLANE (NCLS*SLOTS)
#define OUT_LBL   200000
#define OUT_KEEP  240000
#define FMARGIN   4.0f      // abs err bound of f32 (inter - 0.3*uni) ~0.05 px^2 here; 4.0 = huge safety

__device__ __forceinline__ double read_dim(const void* p) {
  int iv = *(const int*)p;
  if (iv >= 1 && iv <= 1000000) return (double)iv;
  float fv = *(const float*)p;
  if (fv >= 1.0f && fv <= 1000000.0f) return (double)fv;
  return *(const double*)p;
}

// ---- kernel 1: transposed f64 tables: prob_t[cls*R_N+r], tab4[(cls*R_N+r)*4]={dy,dx,exp(dh),exp(dw)}
__global__ __launch_bounds__(256) void prep_kernel(
    const float* __restrict__ score, const float* __restrict__ loc,
    double* __restrict__ tab4, double* __restrict__ prob_t)
{
  int r = blockIdx.x * 256 + threadIdx.x;
  if (r >= R_N) return;
  const float* sc = score + r * C1;
  double m = (double)sc[0];
  #pragma unroll
  for (int k = 1; k < C1; ++k) m = fmax(m, (double)sc[k]);
  double e[C1]; double s = 0.0;
  #pragma unroll
  for (int k = 0; k < C1; ++k) { e[k] = exp((double)sc[k] - m); s += e[k]; }
  for (int c = 0; c < NCLS; ++c)
    prob_t[c * R_N + r] = e[c + 1] / s;
  for (int c = 0; c < NCLS; ++c) {
    const float* l4 = loc + r * 84 + (c + 1) * 4;
    double* o = tab4 + (size_t)(c * R_N + r) * 4;
    o[0] = (double)l4[0];
    o[1] = (double)l4[1];
    o[2] = exp((double)l4[2]);
    o[3] = exp((double)l4[3]);
  }
}

// ---- kernel B: per-class decode + compact + bitonic sort -> sorted SoA arrays in ws ----
__global__ __launch_bounds__(256) void decode_sort_kernel(
    const float* __restrict__ rois,
    const void* __restrict__ hptr, const void* __restrict__ wptr,
    const double* __restrict__ tab4, const double* __restrict__ prob_t,
    double* __restrict__ boxd,   // [4][PLANE] f64 sorted boxes
    float* __restrict__ b5,      // [5][PLANE] f32 sorted boxes+area
    float* __restrict__ probf,   // [PLANE]
    int* __restrict__ vcls)      // [NCLS]
{
  __shared__ double sbd[R_N][4];
  __shared__ ulonglong2 keys[SLOTS];
  __shared__ int wsum[4];

  const int cls = blockIdx.x;
  const int t = threadIdx.x;
  const int lane = t & 63, wid = t >> 6;
  const double H = read_dim(hptr), W = read_dim(wptr);

  // phase 1: decode (coalesced r = t + 256u)
  ulonglong2 rk[8];
  int vmask = 0;
  #pragma unroll
  for (int u = 0; u < 8; ++u) {
    int r = t + 256 * u;
    rk[u] = make_ulonglong2(0ull, 0ull);
    if (r < R_N) {
      double p = prob_t[cls * R_N + r];
      const double* o = tab4 + (size_t)(cls * R_N + r) * 4;
      double dy = o[0], dx = o[1], eh = o[2], ew = o[3];
      double b0 = (double)rois[r*4+0], b1 = (double)rois[r*4+1];
      double b2 = (double)rois[r*4+2], b3 = (double)rois[r*4+3];
      double sh  = b2 - b0,       sw  = b3 - b1;
      double scy = b0 + 0.5*sh,   scx = b1 + 0.5*sw;
      double cy = dy*sh + scy,    cx = dx*sw + scx;
      double hh = eh*sh,          ww = ew*sw;
      double y1 = fmin(fmax(cy - 0.5*hh, 0.0), H);
      double x1 = fmin(fmax(cx - 0.5*ww, 0.0), W);
      double y2 = fmin(fmax(cy + 0.5*hh, 0.0), H);
      double x2 = fmin(fmax(cx + 0.5*ww, 0.0), W);
      sbd[r][0]=y1; sbd[r][1]=x1; sbd[r][2]=y2; sbd[r][3]=x2;
      if (p > 0.05) {
        rk[u] = make_ulonglong2((unsigned long long)__double_as_longlong(p),
                                (unsigned long long)(unsigned int)(~r));
        vmask |= 1 << u;
      }
    }
  }

  // phase 2: compaction (order irrelevant pre-sort)
  int cnt = __popc(vmask);
  int x = cnt;
  #pragma unroll
  for (int off = 1; off < 64; off <<= 1) {
    int y = __shfl_up(x, off);
    if (lane >= off) x += y;
  }
  if (lane == 63) wsum[wid] = x;
  __syncthreads();
  int woff = 0;
  #pragma unroll
  for (int w2 = 0; w2 < 4; ++w2) { int s = wsum[w2]; if (w2 < wid) woff += s; }
  const int V = wsum[0] + wsum[1] + wsum[2] + wsum[3];
  int pos = woff + x - cnt;
  #pragma unroll
  for (int u = 0; u < 8; ++u)
    if ((vmask >> u) & 1) keys[pos++] = rk[u];

  int NSORT = 64; while (NSORT < V) NSORT <<= 1;
  for (int j = V + t; j < NSORT; j += 256)
    keys[j] = make_ulonglong2(0ull, (unsigned long long)(unsigned int)(~(unsigned)j));
  __syncthreads();

  // phase 3: bitonic sort, descending (prob desc, idx asc)
  for (int k = 2; k <= NSORT; k <<= 1) {
    for (int js = k >> 1; js > 0; js >>= 1) {
      for (int p = t; p < (NSORT >> 1); p += 256) {
        int i = ((p & ~(js - 1)) << 1) | (p & (js - 1));
        int j = i | js;
        ulonglong2 a = keys[i], b = keys[j];
        bool altb = (a.x < b.x) || (a.x == b.x && a.y < b.y);
        if (altb == ((i & k) == 0)) { keys[i] = b; keys[j] = a; }
      }
      __syncthreads();
    }
  }

  // epilogue: write sorted SoA arrays
  for (int j = t; j < V; j += 256) {
    int idx = (int)(~(unsigned)keys[j].y);
    double a0=sbd[idx][0], a1=sbd[idx][1], a2=sbd[idx][2], a3=sbd[idx][3];
    int g = cls * SLOTS + j;
    boxd[g]           = a0;
    boxd[PLANE   + g] = a1;
    boxd[2*PLANE + g] = a2;
    boxd[3*PLANE + g] = a3;
    b5[g]           = (float)a0;
    b5[PLANE   + g] = (float)a1;
    b5[2*PLANE + g] = (float)a2;
    b5[3*PLANE + g] = (float)a3;
    b5[4*PLANE + g] = (float)((a2-a0)*(a3-a1));
    probf[g] = (float)__longlong_as_double((long long)keys[j].x);
  }
  if (t == 0) vcls[cls] = V;
}

// ---- kernel C: chunked greedy NMS on sorted slots; writes ALL rows (kept or zero) ----
__global__ __launch_bounds__(256) void nms_kernel(
    float* __restrict__ out,
    const double* __restrict__ boxd, const float* __restrict__ b5,
    const float* __restrict__ probf, const int* __restrict__ vcls)
{
  __shared__ double klist64[2][64][5];
  __shared__ float  klist32[2][64][5];
  __shared__ int kcnt[2];

  const int cls = blockIdx.x;
  const int t = threadIdx.x;
  const int lane = t & 63, wid = t >> 6;
  const int V = vcls[cls];

  float fx0[8], fx1[8], fx2[8], fx3[8], far5[8], pr[8];
  unsigned am = 0, km = 0;
  #pragma unroll
  for (int q = 0; q < 8; ++q) {
    int j = t + 256 * q;
    fx0[q]=fx1[q]=fx2[q]=fx3[q]=far5[q]=pr[q]=0.f;
    if (j < V) {
      int g = cls * SLOTS + j;
      fx0[q]=b5[g]; fx1[q]=b5[PLANE+g]; fx2[q]=b5[2*PLANE+g]; fx3[q]=b5[3*PLANE+g];
      far5[q]=b5[4*PLANE+g]; pr[q]=probf[g];
      am |= 1u << q;
    }
  }

  #pragma unroll
  for (int q = 0; q < 8; ++q) {
    if (256 * q >= V) break;
    for (int sub = 0; sub < 4; ++sub) {
      const int ch = 4 * q + sub;
      if (64 * ch >= V) break;
      const int buf = ch & 1;
      const int chbase = 64 * ch;
      if (wid == sub) {
        const int s = chbase + lane;
        bool a = ((am >> q) & 1u) != 0u;
        float f0=fx0[q], f1=fx1[q], f2=fx2[q], f3=fx3[q], fa=far5[q];
        unsigned long long m = __ballot(a);
        unsigned long long kept = 0;
        while (m) {
          int i = __ffsll(m) - 1;
          m &= m - 1;
          kept |= 1ull << i;
          float k0=__shfl(f0,i), k1=__shfl(f1,i), k2=__shfl(f2,i), k3=__shfl(f3,i), ka=__shfl(fa,i);
          bool aliveL = ((m >> lane) & 1ull) != 0ull;   // implies lane > i
          float ty=fmaxf(k0,f0), tx=fmaxf(k1,f1);
          float by=fminf(k2,f2), bz=fminf(k3,f3);
          float w0=fmaxf(by-ty,0.f), w1=fmaxf(bz-tx,0.f);
          float inter=w0*w1;
          float uni=fmaxf(ka+fa-inter, 1e-9f);
          float rhs=0.3f*uni;
          bool kill = aliveL && (inter > rhs + FMARGIN);
          bool amb  = aliveL && !kill && (inter > rhs - FMARGIN);
          if (__any(amb)) {
            int gi = cls*SLOTS + chbase + i;                  // wave-uniform
            double b0=boxd[gi], b1=boxd[PLANE+gi], b2=boxd[2*PLANE+gi], b3=boxd[3*PLANE+gi];
            if (amb) {
              int gs = cls*SLOTS + s;
              double a0=boxd[gs], a1=boxd[PLANE+gs], a2=boxd[2*PLANE+gs], a3=boxd[3*PLANE+gs];
              double bar=(b2-b0)*(b3-b1), aar=(a2-a0)*(a3-a1);
              double ty_=fmax(b0,a0), tx_=fmax(b1,a1);
              double by_=fmin(b2,a2), bz_=fmin(b3,a3);
              double w0_=fmax(by_-ty_,0.0), w1_=fmax(bz_-tx_,0.0);
              double in_=w0_*w1_;
              double un_=bar+aar-in_;
              if (in_/fmax(un_,1e-9) > 0.3) kill = true;
            }
          }
          m &= ~__ballot(kill);
        }
        am &= ~(1u << q);                          // chunk resolved
        if ((kept >> lane) & 1ull) {
          km |= 1u << q;
          int kpos = (int)__popcll(kept & ((1ull << lane) - 1ull));
          int gs = cls*SLOTS + s;
          double d0=boxd[gs], d1=boxd[PLANE+gs], d2=boxd[2*PLANE+gs], d3=boxd[3*PLANE+gs];
          klist64[buf][kpos][0]=d0; klist64[buf][kpos][1]=d1;
          klist64[buf][kpos][2]=d2; klist64[buf][kpos][3]=d3;
          klist64[buf][kpos][4]=(d2-d0)*(d3-d1);
          klist32[buf][kpos][0]=f0; klist32[buf][kpos][1]=f1;
          klist32[buf][kpos][2]=f2; klist32[buf][kpos][3]=f3; klist32[buf][kpos][4]=fa;
        }
        if (lane == 0) kcnt[buf] = (int)__popcll(kept);
      }
      __syncthreads();
      // cross suppression of future slots (f32 fast, f64 exact fallback)
      const int nk = kcnt[buf];
      const int jmin = 64 * (ch + 1);
      for (int n = 0; n < nk; ++n) {
        float k0=klist32[buf][n][0], k1=klist32[buf][n][1];
        float k2=klist32[buf][n][2], k3=klist32[buf][n][3], ka=klist32[buf][n][4];
        #pragma unroll
        for (int q2 = 0; q2 < 8; ++q2) {
          if (256 * q2 >= V) break;
          int j2 = t + 256 * q2;
          if (((am >> q2) & 1u) && j2 >= jmin) {
            float ty=fmaxf(k0,fx0[q2]), tx=fmaxf(k1,fx1[q2]);
            float by=fminf(k2,fx2[q2]), bz=fminf(k3,fx3[q2]);
            float w0=fmaxf(by-ty,0.f), w1=fmaxf(bz-tx,0.f);
            float inter=w0*w1;
            float uni=fmaxf(ka+far5[q2]-inter, 1e-9f);
            float rhs=0.3f*uni;
            if (inter > rhs + FMARGIN) {
              am &= ~(1u << q2);
            } else if (inter > rhs - FMARGIN) {
              int gs = cls*SLOTS + j2;
              double a0=boxd[gs], a1=boxd[PLANE+gs], a2=boxd[2*PLANE+gs], a3=boxd[3*PLANE+gs];
              double ar_=(a2-a0)*(a3-a1);
              double b0=klist64[buf][n][0], b1=klist64[buf][n][1];
              double b2=klist64[buf][n][2], b3=klist64[buf][n][3], br=klist64[buf][n][4];
              double ty_=fmax(b0,a0), tx_=fmax(b1,a1);
              double by_=fmin(b2,a2), bz_=fmin(b3,a3);
              double w0_=fmax(by_-ty_,0.0), w1_=fmax(bz_-tx_,0.0);
              double in_=w0_*w1_;
              double un_=br+ar_-in_;
              if (in_/fmax(un_,1e-9) > 0.3) am &= ~(1u << q2);
            }
          }
        }
      }
    }
  }

  // final: write all rows (kept = values, else zeros) — replaces the memset dispatch
  #pragma unroll
  for (int q = 0; q < 8; ++q) {
    int j = t + 256 * q;
    if (j < R_N) {
      int row = cls * R_N + j;
      bool k = ((km >> q) & 1u) != 0u;
      out[row*5+0] = k ? fx0[q] : 0.f;
      out[row*5+1] = k ? fx1[q] : 0.f;
      out[row*5+2] = k ? fx2[q] : 0.f;
      out[row*5+3] = k ? fx3[q] : 0.f;
      out[row*5+4] = k ? pr[q]  : 0.f;
      out[OUT_LBL  + row] = k ? (float)(cls + 1) : 0.f;
      out[OUT_KEEP + row] = k ? 1.f : 0.f;
    }
  }
}

// ==================== fallback: R5 monolithic (proven) ====================
__global__ __launch_bounds__(256) void det_kernel(
    const float* __restrict__ rois, const float* __restrict__ loc,
    const float* __restrict__ score,
    const void* __restrict__ hptr, const void* __restrict__ wptr,
    float* __restrict__ out,
    const double* __restrict__ tab4, const double* __restrict__ prob_t,
    int use_ws)
{
  __shared__ double sbd[R_N][4];
  __shared__ ulonglong2 keys[SLOTS];
  __shared__ double klist64[2][64][5];
  __shared__ float  klist32[2][64][5];
  __shared__ int kcnt[2];
  __shared__ int wsum[4];

  const int cls = blockIdx.x;
  const int t = threadIdx.x;
  const int lane = t & 63, wid = t >> 6;
  const double H = read_dim(hptr), W = read_dim(wptr);

  ulonglong2 rk[8];
  int vmask = 0;
  #pragma unroll
  for (int u = 0; u < 8; ++u) {
    int r = t + 256 * u;
    rk[u] = make_ulonglong2(0ull, 0ull);
    if (r < R_N) {
      double p, dy, dx, eh, ew;
      if (use_ws) {
        p = prob_t[cls * R_N + r];
        const double* o = tab4 + (size_t)(cls * R_N + r) * 4;
        dy = o[0]; dx = o[1]; eh = o[2]; ew = o[3];
      } else {
        const float* sc = score + r * C1;
        double m = (double)sc[0];
        #pragma unroll
        for (int k = 1; k < C1; ++k) m = fmax(m, (double)sc[k]);
        double s = 0.0;
        #pragma unroll
        for (int k = 0; k < C1; ++k) s += exp((double)sc[k] - m);
        const float* l4 = loc + r * 84 + (cls + 1) * 4;
        p = exp((double)sc[cls + 1] - m) / s;
        dy = (double)l4[0]; dx = (double)l4[1];
        eh = exp((double)l4[2]); ew = exp((double)l4[3]);
      }
      double b0 = (double)rois[r*4+0], b1 = (double)rois[r*4+1];
      double b2 = (double)rois[r*4+2], b3 = (double)rois[r*4+3];
      double sh  = b2 - b0,       sw  = b3 - b1;
      double scy = b0 + 0.5*sh,   scx = b1 + 0.5*sw;
      double cy = dy*sh + scy,    cx = dx*sw + scx;
      double hh = eh*sh,          ww = ew*sw;
      double y1 = fmin(fmax(cy - 0.5*hh, 0.0), H);
      double x1 = fmin(fmax(cx - 0.5*ww, 0.0), W);
      double y2 = fmin(fmax(cy + 0.5*hh, 0.0), H);
      double x2 = fmin(fmax(cx + 0.5*ww, 0.0), W);
      sbd[r][0]=y1; sbd[r][1]=x1; sbd[r][2]=y2; sbd[r][3]=x2;
      if (p > 0.05) {
        rk[u] = make_ulonglong2((unsigned long long)__double_as_longlong(p),
                                (unsigned long long)(unsigned int)(~r));
        vmask |= 1 << u;
      }
    }
  }

  int cnt = __popc(vmask);
  int x = cnt;
  #pragma unroll
  for (int off = 1; off < 64; off <<= 1) {
    int y = __shfl_up(x, off);
    if (lane >= off) x += y;
  }
  if (lane == 63) wsum[wid] = x;
  __syncthreads();
  int woff = 0;
  #pragma unroll
  for (int w2 = 0; w2 < 4; ++w2) { int s = wsum[w2]; if (w2 < wid) woff += s; }
  const int V = wsum[0] + wsum[1] + wsum[2] + wsum[3];
  int pos = woff + x - cnt;
  #pragma unroll
  for (int u = 0; u < 8; ++u)
    if ((vmask >> u) & 1) keys[pos++] = rk[u];

  int NSORT = 64; while (NSORT < V) NSORT <<= 1;
  for (int j = V + t; j < NSORT; j += 256)
    keys[j] = make_ulonglong2(0ull, (unsigned long long)(unsigned int)(~(unsigned)j));
  __syncthreads();

  for (int k = 2; k <= NSORT; k <<= 1) {
    for (int js = k >> 1; js > 0; js >>= 1) {
      for (int p = t; p < (NSORT >> 1); p += 256) {
        int i = ((p & ~(js - 1)) << 1) | (p & (js - 1));
        int j = i | js;
        ulonglong2 a = keys[i], b = keys[j];
        bool altb = (a.x < b.x) || (a.x == b.x && a.y < b.y);
        if (altb == ((i & k) == 0)) { keys[i] = b; keys[j] = a; }
      }
      __syncthreads();
    }
  }

  int   idx8[8];
  float fx0[8], fx1[8], fx2[8], fx3[8], far5[8];
  unsigned am = 0;
  #pragma unroll
  for (int q = 0; q < 8; ++q) {
    if (256 * q >= V) break;
    int j = t + 256 * q;
    if (j < V) {
      int idx = (int)(~(unsigned)keys[j].y);
      idx8[q] = idx;
      double a0=sbd[idx][0], a1=sbd[idx][1], a2=sbd[idx][2], a3=sbd[idx][3];
      fx0[q]=(float)a0; fx1[q]=(float)a1; fx2[q]=(float)a2; fx3[q]=(float)a3;
      far5[q]=(float)((a2-a0)*(a3-a1));
      am |= 1u << q;
    }
  }

  const int nch = (V + 63) >> 6;
  for (int ch = 0; ch < nch; ++ch) {
    const int buf = ch & 1;
    if (wid == (ch & 3)) {
      const int q = ch >> 2;
      const int s = 64 * ch + lane;
      bool a = ((am >> q) & 1u) != 0u;
      int myidx = 0;
      double d0=0, d1=0, d2=0, d3=0, dar=0;
      if (a) {
        myidx = (int)(~(unsigned)keys[s].y);
        d0=sbd[myidx][0]; d1=sbd[myidx][1]; d2=sbd[myidx][2]; d3=sbd[myidx][3];
        dar = (d2-d0)*(d3-d1);
      }
      float f0=(float)d0, f1=(float)d1, f2=(float)d2, f3=(float)d3, fa=(float)dar;
      unsigned long long m = __ballot(a);
      unsigned long long kept = 0;
      while (m) {
        int i = __ffsll(m) - 1;
        m &= m - 1;
        kept |= 1ull << i;
        float k0=__shfl(f0,i), k1=__shfl(f1,i), k2=__shfl(f2,i), k3=__shfl(f3,i), ka=__shfl(fa,i);
        bool aliveL = ((m >> lane) & 1ull) != 0ull;
        float ty=fmaxf(k0,f0), tx=fmaxf(k1,f1);
        float by=fminf(k2,f2), bz=fminf(k3,f3);
        float w0=fmaxf(by-ty,0.f), w1=fmaxf(bz-tx,0.f);
        float inter=w0*w1;
        float uni=fmaxf(ka+fa-inter, 1e-9f);
        float rhs=0.3f*uni;
        bool kill = aliveL && (inter > rhs + FMARGIN);
        bool amb  = aliveL && !kill && (inter > rhs - FMARGIN);
        if (__any(amb)) {
          int kidx = __shfl(myidx, i);
          double b0=sbd[kidx][0], b1=sbd[kidx][1], b2=sbd[kidx][2], b3=sbd[kidx][3];
          double bar=(b2-b0)*(b3-b1);
          if (amb) {
            double ty_=fmax(b0,d0), tx_=fmax(b1,d1);
            double by_=fmin(b2,d2), bz_=fmin(b3,d3);
            double w0_=fmax(by_-ty_,0.0), w1_=fmax(bz_-tx_,0.0);
            double in_=w0_*w1_;
            double un_=bar+dar-in_;
            if (in_/fmax(un_,1e-9) > 0.3) kill = true;
          }
        }
        m &= ~__ballot(kill);
      }
      am &= ~(1u << q);
      if ((kept >> lane) & 1ull) {
        int kpos = (int)__popcll(kept & ((1ull << lane) - 1ull));
        klist64[buf][kpos][0]=d0; klist64[buf][kpos][1]=d1;
        klist64[buf][kpos][2]=d2; klist64[buf][kpos][3]=d3; klist64[buf][kpos][4]=dar;
        klist32[buf][kpos][0]=f0; klist32[buf][kpos][1]=f1;
        klist32[buf][kpos][2]=f2; klist32[buf][kpos][3]=f3; klist32[buf][kpos][4]=fa;
        double pv = __longlong_as_double((long long)keys[s].x);
        int row = cls * R_N + s;
        out[row*5+0]=(float)d0; out[row*5+1]=(float)d1;
        out[row*5+2]=(float)d2; out[row*5+3]=(float)d3;
        out[row*5+4]=(float)pv;
        out[OUT_LBL  + row] = (float)(cls + 1);
        out[OUT_KEEP + row] = 1.0f;
      }
      if (lane == 0) kcnt[buf] = (int)__popcll(kept);
    }
    __syncthreads();
    const int nk = kcnt[buf];
    const int jmin = 64 * (ch + 1);
    for (int n = 0; n < nk; ++n) {
      float k0=klist32[buf][n][0], k1=klist32[buf][n][1];
      float k2=klist32[buf][n][2], k3=klist32[buf][n][3], ka=klist32[buf][n][4];
      #pragma unroll
      for (int q2 = 0; q2 < 8; ++q2) {
        if (256 * q2 >= V) break;
        int j2 = t + 256 * q2;
        if (((am >> q2) & 1u) && j2 >= jmin) {
          float ty=fmaxf(k0,fx0[q2]), tx=fmaxf(k1,fx1[q2]);
          float by=fminf(k2,fx2[q2]), bz=fminf(k3,fx3[q2]);
          float w0=fmaxf(by-ty,0.f), w1=fmaxf(bz-tx,0.f);
          float inter=w0*w1;
          float uni=fmaxf(ka+far5[q2]-inter, 1e-9f);
          float rhs=0.3f*uni;
          if (inter > rhs + FMARGIN) {
            am &= ~(1u << q2);
          } else if (inter > rhs - FMARGIN) {
            int idx = idx8[q2];
            double a0=sbd[idx][0], a1=sbd[idx][1], a2=sbd[idx][2], a3=sbd[idx][3];
            double ar_=(a2-a0)*(a3-a1);
            double b0=klist64[buf][n][0], b1=klist64[buf][n][1];
            double b2=klist64[buf][n][2], b3=klist64[buf][n][3], br=klist64[buf][n][4];
            double ty_=fmax(b0,a0), tx_=fmax(b1,a1);
            double by_=fmin(b2,a2), bz_=fmin(b3,a3);
            double w0_=fmax(by_-ty_,0.0), w1_=fmax(bz_-tx_,0.0);
            double in_=w0_*w1_;
            double un_=br+ar_-in_;
            if (in_/fmax(un_,1e-9) > 0.3) am &= ~(1u << q2);
          }
        }
      }
    }
  }
}

extern "C" void kernel_launch(void* const* d_in, const int* in_sizes, int n_in,
                              void* d_out, int out_size, void* d_ws, size_t ws_size,
                              hipStream_t stream) {
  const float* rois  = (const float*)d_in[0];
  const float* loc   = (const float*)d_in[1];
  const float* score = (const float*)d_in[2];
  const void*  hp    = d_in[3];
  const void*  wp    = d_in[4];
  float* out = (float*)d_out;

  // ws layout (bytes):
  //   tab4   f64[NCLS*R_N*4]      @ 0         (1,280,000)
  //   prob_t f64[NCLS*R_N]        @ 1,280,000 (  320,000)
  //   boxd   f64[4][NCLS*SLOTS]   @ 1,600,000 (1,310,720)
  //   b5     f32[5][NCLS*SLOTS]   @ 2,910,720 (  819,200)
  //   probf  f32[NCLS*SLOTS]      @ 3,729,920 (  163,840)
  //   vcls   i32[NCLS]            @ 3,893,760 (       80)
  char* wsb = (char*)d_ws;
  double* tab4   = (double*)(wsb + 0);
  double* prob_t = (double*)(wsb + 1280000);
  double* boxd   = (double*)(wsb + 1600000);
  float*  b5     = (float*)(wsb + 2910720);
  float*  probf  = (float*)(wsb + 3729920);
  int*    vcls   = (int*)(wsb + 3893760);
  const size_t WS_SPLIT = 3893840;
  const size_t WS_TAB   = 1600000;

  if (ws_size >= WS_SPLIT) {
    prep_kernel<<<dim3((R_N + 255)/256), dim3(256), 0, stream>>>(score, loc, tab4, prob_t);
    decode_sort_kernel<<<dim3(NCLS), dim3(256), 0, stream>>>(rois, hp, wp, tab4, prob_t,
                                                             boxd, b5, probf, vcls);
    nms_kernel<<<dim3(NCLS), dim3(256), 0, stream>>>(out, boxd, b5, probf, vcls);
  } else if (ws_size >= WS_TAB) {
    hipMemsetAsync(d_out, 0, (size_t)out_size * sizeof(float), stream);
    prep_kernel<<<dim3((R_N + 255)/256), dim3(256), 0, stream>>>(score, loc, tab4, prob_t);
    det_kernel<<<dim3(NCLS), dim3(256), 0, stream>>>(rois, loc, score, hp, wp, out,
                                                     tab4, prob_t, 1);
  } else {
    hipMemsetAsync(d_out, 0, (size_t)out_size * sizeof(float), stream);
    det_kernel<<<dim3(NCLS), dim3(256), 0, stream>>>(rois, loc, score, hp, wp, out,
                                                     (const double*)nullptr, (const double*)nullptr, 0);
  }
}